// Round 6
// baseline (1159.820 us; speedup 1.0000x reference)
//
#include <hip/hip_runtime.h>
#include <hip/hip_bf16.h>
#include <math.h>

#define T_STEPS 12
#define NNODES  20000
#define NEDGES  320000
#define MPAD    20032
#define FIN     128
#define HG      256
#define RS_STRIDE 20032

typedef unsigned short u16;
typedef unsigned int   u32;
using bf16x8 = __attribute__((ext_vector_type(8))) short;
using f32x4  = __attribute__((ext_vector_type(4))) float;

__device__ __forceinline__ float bf2f(u16 u) {
    union { u32 i; float f; } v; v.i = ((u32)u) << 16; return v.f;
}
__device__ __forceinline__ u16 f2bf(float f) {
    union { float f; u32 i; } v; v.f = f;
    u32 r = v.i + 0x7fffu + ((v.i >> 16) & 1u);
    return (u16)(r >> 16);
}
__device__ __forceinline__ u16 f2h(float f) {
    _Float16 h = (_Float16)f; u16 u; __builtin_memcpy(&u, &h, 2); return u;
}
__device__ __forceinline__ float h2f(u16 u) {
    _Float16 h; __builtin_memcpy(&h, &u, 2); return (float)h;
}
__device__ __forceinline__ void gload16(const void* g, void* l) {
    __builtin_amdgcn_global_load_lds(
        (const __attribute__((address_space(1))) u32*)g,
        (__attribute__((address_space(3))) u32*)l, 16, 0, 0);
}
__device__ __forceinline__ float sigm(float x) { return 1.f / (1.f + expf(-x)); }
__device__ __forceinline__ void astore(float* p, float v) {
    __hip_atomic_store(p, v, __ATOMIC_RELAXED, __HIP_MEMORY_SCOPE_AGENT);
}
__device__ __forceinline__ float aload(const float* p) {
    return __hip_atomic_load(p, __ATOMIC_RELAXED, __HIP_MEMORY_SCOPE_AGENT);
}

// ---------------- CSR build (verified R1-R5) ----------------

__global__ void hist_kernel(const int* __restrict__ edges, int* __restrict__ hist) {
    int idx = blockIdx.x * blockDim.x + threadIdx.x;
    if (idx >= T_STEPS * NEDGES) return;
    int t = idx / NEDGES, e = idx - t * NEDGES;
    int d = edges[t * 2 * NEDGES + NEDGES + e];
    atomicAdd(&hist[t * NNODES + d], 1);
}

__global__ void __launch_bounds__(1024) scan_kernel(int* __restrict__ hist,
        int* __restrict__ rowstart, float* __restrict__ dinv) {
    int t = blockIdx.x;
    int tid = threadIdx.x;
    __shared__ int buf[1024];
    __shared__ int carry_s;
    if (tid == 0) carry_s = 0;
    __syncthreads();
    for (int base = 0; base < NNODES; base += 1024) {
        int i = base + tid;
        int v = (i < NNODES) ? hist[t * NNODES + i] : 0;
        buf[tid] = v;
        __syncthreads();
        for (int off = 1; off < 1024; off <<= 1) {
            int add = (tid >= off) ? buf[tid - off] : 0;
            __syncthreads();
            buf[tid] += add;
            __syncthreads();
        }
        int incl = buf[tid];
        int excl = incl - v + carry_s;
        if (i < NNODES) {
            rowstart[t * RS_STRIDE + i] = excl;
            dinv[t * NNODES + i] = rsqrtf((float)(v + 1));
            hist[t * NNODES + i] = 0;
        }
        __syncthreads();
        if (tid == 1023) carry_s += incl;
        __syncthreads();
    }
    if (tid == 0) rowstart[t * RS_STRIDE + NNODES] = carry_s;
}

__global__ void fill_kernel(const int* __restrict__ edges, const int* __restrict__ rowstart,
        int* __restrict__ cursor, int* __restrict__ col) {
    int idx = blockIdx.x * blockDim.x + threadIdx.x;
    if (idx >= T_STEPS * NEDGES) return;
    int t = idx / NEDGES, e = idx - t * NEDGES;
    int s = edges[t * 2 * NEDGES + e];
    int d = edges[t * 2 * NEDGES + NEDGES + e];
    int pos = rowstart[t * RS_STRIDE + d] + atomicAdd(&cursor[t * NNODES + d], 1);
    col[t * NEDGES + pos] = s;
}

// ---------------- conversions ----------------

__global__ void convw_kernel(const float* __restrict__ W, u16* __restrict__ Wt, int K) {
    int idx = blockIdx.x * blockDim.x + threadIdx.x;
    int n = idx / K, k = idx - n * K;
    Wt[idx] = f2bf(W[k * HG + n]);
}

// x fp32 -> bf16 premultiplied by dinv
__global__ void x2bf_kernel(const float* __restrict__ x, const float* __restrict__ dinv,
        u16* __restrict__ xb) {
    int idx = blockIdx.x * blockDim.x + threadIdx.x;
    int row = idx >> 5, q = (idx & 31) << 2;
    float dn = dinv[row];
    float4 v = *(const float4*)&x[(size_t)row * FIN + q];
    ushort4 o;
    o.x = f2bf(dn * v.x); o.y = f2bf(dn * v.y);
    o.z = f2bf(dn * v.z); o.w = f2bf(dn * v.w);
    *(ushort4*)&xb[(size_t)row * FIN + q] = o;
}

// ---------------- XCD-sliced pull aggregation ----------------
// Feature dim split into 64-dim slices; blockIdx%NSLICE = slice so that (with the
// empirical round-robin block->XCD mapping) each XCD's L2 only holds its slice
// (~2.5 MB < 4 MB) -> gather becomes L2-resident. Wave = 2 nodes x 32 lanes,
// 64-thread blocks (no intra-block imbalance). 16-deep batched gather.
// rows are PRE-SCALED by dinv: out[d] = dinv[d]*(row[d] + sum_{s->d} row[s]).

template <int DIMS, int NSLICE, bool SRC_MPAD>
__global__ void __launch_bounds__(64) agg_slice(const u16* __restrict__ src,
        const int* __restrict__ rowstart, const int* __restrict__ col,
        const float* __restrict__ dinv, u16* __restrict__ out) {
    int bid = blockIdx.x;
    int slice = bid % NSLICE;
    int rest = bid / NSLICE;
    constexpr int NP = MPAD / 2;
    int np = rest % NP;
    int t = rest / NP;
    int half = threadIdx.x >> 5, l = threadIdx.x & 31;
    int node = np * 2 + half;
    int dbase = slice * 64 + l * 2;
    u16* orow = out + ((size_t)t * MPAD + node) * DIMS + dbase;
    if (node >= NNODES) { *(u32*)orow = 0; return; }
    const u16* xt = src + (size_t)t * (SRC_MPAD ? MPAD : NNODES) * DIMS + dbase;
    const int* cb = col + (size_t)t * NEDGES;
    u32 pv = *(const u32*)&xt[(size_t)node * DIMS];
    float ax = bf2f((u16)pv), ay = bf2f((u16)(pv >> 16));
    int s0 = rowstart[t * RS_STRIDE + node], s1 = rowstart[t * RS_STRIDE + node + 1];
    int e = s0;
    for (; e + 16 <= s1; e += 16) {
        int ix[16]; u32 rv[16];
#pragma unroll
        for (int j = 0; j < 16; ++j) ix[j] = cb[e + j];
#pragma unroll
        for (int j = 0; j < 16; ++j) rv[j] = *(const u32*)&xt[(size_t)ix[j] * DIMS];
#pragma unroll
        for (int j = 0; j < 16; ++j) {
            ax += bf2f((u16)rv[j]); ay += bf2f((u16)(rv[j] >> 16));
        }
    }
    for (; e + 4 <= s1; e += 4) {
        int ix[4]; u32 rv[4];
#pragma unroll
        for (int j = 0; j < 4; ++j) ix[j] = cb[e + j];
#pragma unroll
        for (int j = 0; j < 4; ++j) rv[j] = *(const u32*)&xt[(size_t)ix[j] * DIMS];
#pragma unroll
        for (int j = 0; j < 4; ++j) {
            ax += bf2f((u16)rv[j]); ay += bf2f((u16)(rv[j] >> 16));
        }
    }
    for (; e < s1; ++e) {
        u32 rv = *(const u32*)&xt[(size_t)cb[e] * DIMS];
        ax += bf2f((u16)rv); ay += bf2f((u16)(rv >> 16));
    }
    float dn = dinv[t * NNODES + node];
    *(u32*)orow = (u32)f2bf(dn * ax) | ((u32)f2bf(dn * ay) << 16);
}

// ---------------- bf16 MFMA GEMM (verified R2-R5 core) ----------------

template <int K, bool POOL>
__global__ __launch_bounds__(256) void gemm_bf16(
        const u16* __restrict__ A, const u16* __restrict__ Bt,
        const float* __restrict__ bias, const float* __restrict__ dscale,
        u16* __restrict__ C, float* __restrict__ pool) {
    __shared__ u16 As[64 * 64];
    __shared__ u16 Bs[64 * 64];
    __shared__ float csum[64];
    int tid = threadIdx.x;
    int bm = blockIdx.x * 64, bn = blockIdx.y * 64;
    int t8 = tid >> 3, sl = tid & 7;
    int lane = tid & 63, wid = tid >> 6;
    int wr = wid >> 1, wc = wid & 1;
    int r0 = lane & 15, gq = lane >> 4;
    int tblk = blockIdx.x / 313;

    f32x4 acc[2][2] = {};

    for (int k0 = 0; k0 < K; k0 += 64) {
#pragma unroll
        for (int i = 0; i < 2; ++i) {
            int r = i * 32 + t8;
            int ch = sl ^ (r & 7);
            gload16(A  + (size_t)(bm + r) * K + k0 + ch * 8, &As[i * 2048 + tid * 8]);
            gload16(Bt + (size_t)(bn + r) * K + k0 + ch * 8, &Bs[i * 2048 + tid * 8]);
        }
        __syncthreads();
#pragma unroll
        for (int kk = 0; kk < 2; ++kk) {
            bf16x8 a[2], b[2];
#pragma unroll
            for (int mi = 0; mi < 2; ++mi) {
                int R = wr * 32 + mi * 16 + r0;
                int s = (kk * 4 + gq) ^ (R & 7);
                a[mi] = *(const bf16x8*)&As[R * 64 + s * 8];
            }
#pragma unroll
            for (int ni = 0; ni < 2; ++ni) {
                int R = wc * 32 + ni * 16 + r0;
                int s = (kk * 4 + gq) ^ (R & 7);
                b[ni] = *(const bf16x8*)&Bs[R * 64 + s * 8];
            }
#pragma unroll
            for (int mi = 0; mi < 2; ++mi)
#pragma unroll
                for (int ni = 0; ni < 2; ++ni)
                    acc[mi][ni] = __builtin_amdgcn_mfma_f32_16x16x32_bf16(
                        a[mi], b[ni], acc[mi][ni], 0, 0, 0);
        }
        __syncthreads();
    }

    if (!POOL) {
#pragma unroll
        for (int ni = 0; ni < 2; ++ni) {
            int colg = bn + wc * 32 + ni * 16 + r0;
            float b = bias[colg];
#pragma unroll
            for (int mi = 0; mi < 2; ++mi) {
                int rbase = bm + wr * 32 + mi * 16 + gq * 4;
#pragma unroll
                for (int q = 0; q < 4; ++q) {
                    int row = rbase + q;
                    int rloc = row - tblk * MPAD;
                    float sc = (rloc < NNODES) ? dscale[tblk * NNODES + rloc] : 0.f;
                    C[(size_t)row * HG + colg] = f2bf(sc * fmaxf(acc[mi][ni][q] + b, 0.f));
                }
            }
        }
    } else {
        if (tid < 64) csum[tid] = 0.f;
        __syncthreads();
#pragma unroll
        for (int ni = 0; ni < 2; ++ni) {
            int lcol = wc * 32 + ni * 16 + r0;
            float b = bias[bn + lcol];
            float s = 0.f;
#pragma unroll
            for (int mi = 0; mi < 2; ++mi) {
                int rbase = bm + wr * 32 + mi * 16 + gq * 4;
#pragma unroll
                for (int q = 0; q < 4; ++q) {
                    int row = rbase + q;
                    int rloc = row - tblk * MPAD;
                    if (rloc < NNODES) s += fmaxf(acc[mi][ni][q] + b, 0.f);
                }
            }
            atomicAdd(&csum[lcol], s);
        }
        __syncthreads();
        if (tid < 64) atomicAdd(&pool[tblk * HG + bn + tid], csum[tid]);
    }
}

// ---------------- layer-0 input projection (verified R2-R5) ----------------

__global__ void __launch_bounds__(128) pre0_kernel(const float* __restrict__ pooled,
        const float* __restrict__ Wih0, const float* __restrict__ bih0,
        const float* __restrict__ bhh0, float* __restrict__ pre0) {
    int j = blockIdx.x * 128 + threadIdx.x;
    const float4* w = (const float4*)(Wih0 + (size_t)j * HG);
    float acc[T_STEPS];
#pragma unroll
    for (int t = 0; t < T_STEPS; ++t) acc[t] = 0.f;
    for (int i = 0; i < 64; ++i) {
        float4 wv = w[i];
#pragma unroll
        for (int t = 0; t < T_STEPS; ++t) {
            float4 pv = *(const float4*)&pooled[t * HG + i * 4];
            acc[t] += pv.x * wv.x + pv.y * wv.y + pv.z * wv.z + pv.w * wv.w;
        }
    }
    float b = bih0[j] + bhh0[j];
#pragma unroll
    for (int t = 0; t < T_STEPS; ++t)
        pre0[t * 1024 + j] = acc[t] * (1.f / (float)NNODES) + b;
}

// ---------------- 4-block cooperative LSTM (verified R5) ----------------

__device__ __forceinline__ void run_layer(const float* __restrict__ W,
        const float* preSrc, int preStride,
        int r, int tid, int b, int sbase, bool save_hseq,
        float* hl, float* garr,
        float* hbuf, float* hseq_glob, int* flags) {
    int u = tid & 63;
    u32 wreg[128];
    {
        const float4* src = (const float4*)(W + (size_t)r * HG);
#pragma unroll
        for (int i = 0; i < 64; ++i) {
            float4 v = src[i];
            wreg[2 * i]     = (u32)f2h(v.x) | ((u32)f2h(v.y) << 16);
            wreg[2 * i + 1] = (u32)f2h(v.z) | ((u32)f2h(v.w) << 16);
        }
    }
    float c = 0.f;
    hl[tid] = 0.f;
    __syncthreads();
    for (int t = 0; t < T_STEPS; ++t) {
        int s = sbase + t + 1;
        float pv = preSrc[t * preStride];
        float acc = 0.f;
#pragma unroll
        for (int k2 = 0; k2 < 128; ++k2) {
            u32 w = wreg[k2];
            float2 hv = *(const float2*)&hl[k2 * 2];
            acc += h2f((u16)w) * hv.x + h2f((u16)(w >> 16)) * hv.y;
        }
        garr[tid] = acc + pv;
        __syncthreads();
        if (tid < 64) {
            float ig = sigm(garr[u]);
            float fg = sigm(garr[64 + u]);
            float gg = tanhf(garr[128 + u]);
            float og = sigm(garr[192 + u]);
            c = fg * c + ig * gg;
            float hn = og * tanhf(c);
            astore(&hbuf[(s & 1) * 256 + b * 64 + u], hn);
            if (save_hseq) astore(&hseq_glob[t * 256 + b * 64 + u], hn);
        }
        if (tid == 0)
            __hip_atomic_store(&flags[b], s, __ATOMIC_RELEASE, __HIP_MEMORY_SCOPE_AGENT);
        if (tid < 4) {
            while (__hip_atomic_load(&flags[tid], __ATOMIC_ACQUIRE,
                                     __HIP_MEMORY_SCOPE_AGENT) < s)
                __builtin_amdgcn_s_sleep(1);
        }
        __syncthreads();
        hl[tid] = aload(&hbuf[(s & 1) * 256 + tid]);
        __syncthreads();
    }
}

__global__ void __launch_bounds__(256, 1) lstm4(
        const float* __restrict__ pre0,
        const float* __restrict__ Whh0, const float* __restrict__ Wih1,
        const float* __restrict__ Whh1,
        const float* __restrict__ bih1, const float* __restrict__ bhh1,
        const float* __restrict__ Wlin, const float* __restrict__ blin,
        float* hbuf, float* hseq_glob, int* flags,
        float* __restrict__ out) {
    __shared__ float hseqL[T_STEPS * 256];
    __shared__ float pre1L[T_STEPS * 256];
    __shared__ float hl[256];
    __shared__ float garr[256];
    int tid = threadIdx.x;
    int b = blockIdx.x;
    int g = tid >> 6, u = tid & 63;
    int r = g * 256 + b * 64 + u;

    run_layer(Whh0, pre0 + r, 1024, r, tid, b, 0, true,
              hl, garr, hbuf, hseq_glob, flags);

    for (int i = tid; i < T_STEPS * 256; i += 256)
        hseqL[i] = aload(&hseq_glob[i]);
    __syncthreads();

    {
        float pre1[T_STEPS];
#pragma unroll
        for (int t = 0; t < T_STEPS; ++t) pre1[t] = 0.f;
        const float4* src = (const float4*)(Wih1 + (size_t)r * HG);
        for (int i = 0; i < 64; ++i) {
            float4 wv = src[i];
#pragma unroll
            for (int t = 0; t < T_STEPS; ++t) {
                float4 hv = *(const float4*)&hseqL[t * 256 + i * 4];
                pre1[t] += wv.x * hv.x + wv.y * hv.y + wv.z * hv.z + wv.w * hv.w;
            }
        }
        float bias1 = bih1[r] + bhh1[r];
        __syncthreads();
#pragma unroll
        for (int t = 0; t < T_STEPS; ++t) pre1L[t * 256 + tid] = pre1[t] + bias1;
        __syncthreads();
    }

    run_layer(Whh1, pre1L + tid, 256, r, tid, b, T_STEPS, false,
              hl, garr, hbuf, hseq_glob, flags);

    if (b == 0) {
        float hv = hl[tid];
        for (int j = 0; j < 8; ++j) {
            garr[tid] = hv * Wlin[j * 256 + tid];
            __syncthreads();
            if (tid < 128) garr[tid] += garr[tid + 128];
            __syncthreads();
            if (tid < 64) {
                float v = garr[tid] + garr[tid + 64];
                for (int off = 32; off; off >>= 1) v += __shfl_down(v, off);
                if (tid == 0) out[j] = v + blin[j];
            }
            __syncthreads();
        }
    }
}

// ---------------- orchestration ----------------

extern "C" void kernel_launch(void* const* d_in, const int* in_sizes, int n_in,
                              void* d_out, int out_size, void* d_ws, size_t ws_size,
                              hipStream_t stream) {
    const float* x    = (const float*)d_in[0];
    const int*   edges= (const int*)d_in[1];
    const float* W1   = (const float*)d_in[3];
    const float* b1   = (const float*)d_in[4];
    const float* W2   = (const float*)d_in[5];
    const float* b2   = (const float*)d_in[6];
    const float* Wih0 = (const float*)d_in[7];
    const float* Whh0 = (const float*)d_in[8];
    const float* bih0 = (const float*)d_in[9];
    const float* bhh0 = (const float*)d_in[10];
    const float* Wih1 = (const float*)d_in[11];
    const float* Whh1 = (const float*)d_in[12];
    const float* bih1 = (const float*)d_in[13];
    const float* bhh1 = (const float*)d_in[14];
    const float* Wlin = (const float*)d_in[15];
    const float* blin = (const float*)d_in[16];
    (void)in_sizes; (void)n_in; (void)out_size;

    char* p = (char*)d_ws;
    auto alloc = [&](size_t bytes) -> char* {
        char* q = p; p += (bytes + 255) & ~(size_t)255; return q;
    };
    int*   hist     = (int*)  alloc(sizeof(int)   * T_STEPS * NNODES);
    int*   rowstart = (int*)  alloc(sizeof(int)   * T_STEPS * RS_STRIDE);
    float* dinv     = (float*)alloc(sizeof(float) * T_STEPS * NNODES);
    int*   col      = (int*)  alloc(sizeof(int)   * T_STEPS * NEDGES);
    float* pooled   = (float*)alloc(sizeof(float) * T_STEPS * HG);
    u16*   W1t      = (u16*)  alloc(sizeof(u16)   * HG * FIN);
    u16*   W2t      = (u16*)  alloc(sizeof(u16)   * HG * HG);
    float* pre0     = (float*)alloc(sizeof(float) * T_STEPS * 1024);
    float* hbuf     = (float*)alloc(sizeof(float) * 2 * 256);
    float* hseq_g   = (float*)alloc(sizeof(float) * T_STEPS * 256);
    int*   flags    = (int*)  alloc(sizeof(int)   * 4);
    size_t fixed_used = (size_t)(p - (char*)d_ws);

    const size_t xb_bytes  = sizeof(u16) * (size_t)T_STEPS * NNODES * FIN;
    const size_t per_g     = (size_t)MPAD * HG * 2 * 2;
    const size_t slack     = 4096 * 16;
    static const int gopts[6] = {12, 6, 4, 3, 2, 1};
    int G = 1;
    for (int i = 0; i < 6; ++i)
        if (fixed_used + xb_bytes + per_g * gopts[i] + slack <= ws_size) { G = gopts[i]; break; }
    u16* xb   = (u16*)alloc(xb_bytes);
    u16* h1b  = (u16*)alloc(sizeof(u16) * (size_t)G * MPAD * HG);
    u16* aggu = (u16*)alloc(sizeof(u16) * (size_t)G * MPAD * HG);

    hipMemsetAsync(hist, 0, sizeof(int) * T_STEPS * NNODES, stream);
    hipMemsetAsync(pooled, 0, sizeof(float) * T_STEPS * HG, stream);
    hipMemsetAsync(flags, 0, sizeof(int) * 4, stream);

    int tot = T_STEPS * NEDGES;
    hist_kernel<<<(tot + 255) / 256, 256, 0, stream>>>(edges, hist);
    scan_kernel<<<T_STEPS, 1024, 0, stream>>>(hist, rowstart, dinv);
    fill_kernel<<<(tot + 255) / 256, 256, 0, stream>>>(edges, rowstart, hist, col);
    convw_kernel<<<HG * FIN / 256, 256, 0, stream>>>(W1, W1t, FIN);
    convw_kernel<<<HG * HG  / 256, 256, 0, stream>>>(W2, W2t, HG);
    x2bf_kernel<<<T_STEPS * NNODES * 32 / 256, 256, 0, stream>>>(x, dinv, xb);

    for (int g = 0; g < T_STEPS / G; ++g) {
        int t0 = g * G;
        const u16*   xbg = xb + (size_t)t0 * NNODES * FIN;
        const int*   rsg = rowstart + (size_t)t0 * RS_STRIDE;
        const int*   clg = col + (size_t)t0 * NEDGES;
        const float* dvg = dinv + (size_t)t0 * NNODES;
        // agg1: 2 slices x (MPAD/2) node-pairs x G timesteps, 64-thread blocks
        agg_slice<FIN, 2, false><<<G * 2 * (MPAD / 2), 64, 0, stream>>>(
                xbg, rsg, clg, dvg, aggu);
        gemm_bf16<FIN, false><<<dim3(G * 313, 4), 256, 0, stream>>>(aggu, W1t, b1, dvg,
                h1b, nullptr);
        // agg2: 4 slices
        agg_slice<HG, 4, true><<<G * 4 * (MPAD / 2), 64, 0, stream>>>(
                h1b, rsg, clg, dvg, aggu);
        gemm_bf16<HG, true><<<dim3(G * 313, 4), 256, 0, stream>>>(aggu, W2t, b2, nullptr,
                nullptr, pooled + (size_t)t0 * HG);
    }
    pre0_kernel<<<8, 128, 0, stream>>>(pooled, Wih0, bih0, bhh0, pre0);
    lstm4<<<4, 256, 0, stream>>>(pre0, Whh0, Wih1, Whh1, bih1, bhh1, Wlin, blin,
                                 hbuf, hseq_g, flags, (float*)d_out);
}

// Round 7
// 1155.317 us; speedup vs baseline: 1.0039x; 1.0039x over previous
//
#include <hip/hip_runtime.h>
#include <hip/hip_bf16.h>
#include <math.h>

#define T_STEPS 12
#define NNODES  20000
#define NEDGES  320000
#define MPAD    20032
#define FIN     128
#define HG      256
#define RS_STRIDE 20032

typedef unsigned short u16;
typedef unsigned int   u32;
using bf16x8 = __attribute__((ext_vector_type(8))) short;
using f32x4  = __attribute__((ext_vector_type(4))) float;

__device__ __forceinline__ float bf2f(u16 u) {
    union { u32 i; float f; } v; v.i = ((u32)u) << 16; return v.f;
}
__device__ __forceinline__ u16 f2bf(float f) {
    union { float f; u32 i; } v; v.f = f;
    u32 r = v.i + 0x7fffu + ((v.i >> 16) & 1u);
    return (u16)(r >> 16);
}
__device__ __forceinline__ u16 f2h(float f) {
    _Float16 h = (_Float16)f; u16 u; __builtin_memcpy(&u, &h, 2); return u;
}
__device__ __forceinline__ float h2f(u16 u) {
    _Float16 h; __builtin_memcpy(&h, &u, 2); return (float)h;
}
__device__ __forceinline__ void gload16(const void* g, void* l) {
    __builtin_amdgcn_global_load_lds(
        (const __attribute__((address_space(1))) u32*)g,
        (__attribute__((address_space(3))) u32*)l, 16, 0, 0);
}
__device__ __forceinline__ float sigm(float x) { return 1.f / (1.f + expf(-x)); }
__device__ __forceinline__ void astore(float* p, float v) {
    __hip_atomic_store(p, v, __ATOMIC_RELAXED, __HIP_MEMORY_SCOPE_AGENT);
}
__device__ __forceinline__ float aload(const float* p) {
    return __hip_atomic_load(p, __ATOMIC_RELAXED, __HIP_MEMORY_SCOPE_AGENT);
}

// ---------------- CSR build ----------------

__global__ void hist_kernel(const int* __restrict__ edges, int* __restrict__ hist) {
    int idx = blockIdx.x * blockDim.x + threadIdx.x;
    if (idx >= T_STEPS * NEDGES) return;
    int t = idx / NEDGES, e = idx - t * NEDGES;
    int d = edges[t * 2 * NEDGES + NEDGES + e];
    atomicAdd(&hist[t * NNODES + d], 1);
}

// shfl-based block scan: 3 syncs per 1024-chunk (was ~22)
__global__ void __launch_bounds__(1024) scan_kernel(int* __restrict__ hist,
        int* __restrict__ rowstart, float* __restrict__ dinv) {
    int t = blockIdx.x;
    int tid = threadIdx.x;
    int wid = tid >> 6, lane = tid & 63;
    __shared__ int wsum[16];
    __shared__ int carry_s;
    if (tid == 0) carry_s = 0;
    __syncthreads();
    for (int base = 0; base < NNODES; base += 1024) {
        int i = base + tid;
        int orig = (i < NNODES) ? hist[t * NNODES + i] : 0;
        int v = orig;
#pragma unroll
        for (int off = 1; off < 64; off <<= 1) {
            int n = __shfl_up(v, off);
            if (lane >= off) v += n;
        }
        if (lane == 63) wsum[wid] = v;
        __syncthreads();
        if (wid == 0 && lane < 16) {
            int s = wsum[lane];
#pragma unroll
            for (int off = 1; off < 16; off <<= 1) {
                int n = __shfl_up(s, off);
                if (lane >= off) s += n;
            }
            wsum[lane] = s;
        }
        __syncthreads();
        int incl = v + (wid > 0 ? wsum[wid - 1] : 0) + carry_s;
        int excl = incl - orig;
        if (i < NNODES) {
            rowstart[t * RS_STRIDE + i] = excl;
            dinv[t * NNODES + i] = rsqrtf((float)(orig + 1));
            hist[t * NNODES + i] = 0;
        }
        __syncthreads();
        if (tid == 0) carry_s += wsum[15];
        __syncthreads();
    }
    if (tid == 0) rowstart[t * RS_STRIDE + NNODES] = carry_s;
}

__global__ void fill_kernel(const int* __restrict__ edges, const int* __restrict__ rowstart,
        int* __restrict__ cursor, int* __restrict__ col) {
    int idx = blockIdx.x * blockDim.x + threadIdx.x;
    if (idx >= T_STEPS * NEDGES) return;
    int t = idx / NEDGES, e = idx - t * NEDGES;
    int s = edges[t * 2 * NEDGES + e];
    int d = edges[t * 2 * NEDGES + NEDGES + e];
    int pos = rowstart[t * RS_STRIDE + d] + atomicAdd(&cursor[t * NNODES + d], 1);
    col[t * NEDGES + pos] = s;
}

// ---------------- conversions ----------------

__global__ void convw_kernel(const float* __restrict__ W, u16* __restrict__ Wt, int K) {
    int idx = blockIdx.x * blockDim.x + threadIdx.x;
    int n = idx / K, k = idx - n * K;
    Wt[idx] = f2bf(W[k * HG + n]);
}

__global__ void x2bf_kernel(const float* __restrict__ x, const float* __restrict__ dinv,
        u16* __restrict__ xb) {
    int idx = blockIdx.x * blockDim.x + threadIdx.x;
    int row = idx >> 5, q = (idx & 31) << 2;
    float dn = dinv[row];
    float4 v = *(const float4*)&x[(size_t)row * FIN + q];
    ushort4 o;
    o.x = f2bf(dn * v.x); o.y = f2bf(dn * v.y);
    o.z = f2bf(dn * v.z); o.w = f2bf(dn * v.w);
    *(ushort4*)&xb[(size_t)row * FIN + q] = o;
}

// ---------------- XCD-sliced pull aggregation, 4 nodes/wave, 16-deep dwordx2 ----------------
// slice = bid % NSLICE keeps each XCD's L2 on one 64-dim slice (2.56 MB/t).
// Wave = 4 nodes x 16 lanes x 4 dims (8 B/lane): 16-deep batch = 8 KB in flight/wave.
// rows PRE-SCALED by dinv: out[d] = dinv[d]*(row[d] + sum_{s->d} row[s]).

template <int DIMS, int NSLICE, bool SRC_MPAD>
__global__ void __launch_bounds__(64) agg_slice(const u16* __restrict__ src,
        const int* __restrict__ rowstart, const int* __restrict__ col,
        const float* __restrict__ dinv, u16* __restrict__ out) {
    int bid = blockIdx.x;
    int slice = bid % NSLICE;
    int rest = bid / NSLICE;
    constexpr int NQ = MPAD / 4;
    int nq = rest % NQ;
    int t = rest / NQ;
    int lane = threadIdx.x;
    int quarter = lane >> 4, l4 = lane & 15;
    int node = nq * 4 + quarter;
    int dbase = slice * 64 + l4 * 4;
    u16* orow = out + ((size_t)t * MPAD + node) * DIMS + dbase;
    if (node >= NNODES) { *(uint2*)orow = make_uint2(0u, 0u); return; }
    const u16* xt = src + (size_t)t * (SRC_MPAD ? MPAD : NNODES) * DIMS + dbase;
    const int* cb = col + (size_t)t * NEDGES;
    uint2 pv = *(const uint2*)&xt[(size_t)node * DIMS];
    float a0 = bf2f((u16)pv.x), a1 = bf2f((u16)(pv.x >> 16));
    float a2 = bf2f((u16)pv.y), a3 = bf2f((u16)(pv.y >> 16));
    int s0 = rowstart[t * RS_STRIDE + node], s1 = rowstart[t * RS_STRIDE + node + 1];
    int e = s0;
    for (; e + 16 <= s1; e += 16) {
        int ix[16]; uint2 rv[16];
#pragma unroll
        for (int j = 0; j < 16; ++j) ix[j] = cb[e + j];
#pragma unroll
        for (int j = 0; j < 16; ++j) rv[j] = *(const uint2*)&xt[(size_t)ix[j] * DIMS];
#pragma unroll
        for (int j = 0; j < 16; ++j) {
            a0 += bf2f((u16)rv[j].x); a1 += bf2f((u16)(rv[j].x >> 16));
            a2 += bf2f((u16)rv[j].y); a3 += bf2f((u16)(rv[j].y >> 16));
        }
    }
    for (; e + 4 <= s1; e += 4) {
        int ix[4]; uint2 rv[4];
#pragma unroll
        for (int j = 0; j < 4; ++j) ix[j] = cb[e + j];
#pragma unroll
        for (int j = 0; j < 4; ++j) rv[j] = *(const uint2*)&xt[(size_t)ix[j] * DIMS];
#pragma unroll
        for (int j = 0; j < 4; ++j) {
            a0 += bf2f((u16)rv[j].x); a1 += bf2f((u16)(rv[j].x >> 16));
            a2 += bf2f((u16)rv[j].y); a3 += bf2f((u16)(rv[j].y >> 16));
        }
    }
    for (; e < s1; ++e) {
        uint2 rv = *(const uint2*)&xt[(size_t)cb[e] * DIMS];
        a0 += bf2f((u16)rv.x); a1 += bf2f((u16)(rv.x >> 16));
        a2 += bf2f((u16)rv.y); a3 += bf2f((u16)(rv.y >> 16));
    }
    float dn = dinv[t * NNODES + node];
    uint2 o;
    o.x = (u32)f2bf(dn * a0) | ((u32)f2bf(dn * a1) << 16);
    o.y = (u32)f2bf(dn * a2) | ((u32)f2bf(dn * a3) << 16);
    *(uint2*)orow = o;
}

// ---------------- bf16 MFMA GEMM, 64M x 256N tile (A read once) ----------------
// A [G*MPAD][K] bf16 (pad rows zero), Bt [256][K] bf16. BK=64, 4 waves; wave w owns
// cols w*64..w*64+63 (4x4 16x16 frags). LDS XOR-slot swizzle as verified R2-R6.
// !POOL: C[row] = bf16(dscale[row]*relu(acc+bias)); POOL: per-t column sums.

template <int K, bool POOL>
__global__ __launch_bounds__(256) void gemm_bf16(
        const u16* __restrict__ A, const u16* __restrict__ Bt,
        const float* __restrict__ bias, const float* __restrict__ dscale,
        u16* __restrict__ C, float* __restrict__ pool) {
    __shared__ u16 As[64 * 64];      // 8 KB
    __shared__ u16 Bs[256 * 64];     // 32 KB
    __shared__ float csum[HG];
    int tid = threadIdx.x;
    int bm = blockIdx.x * 64;
    int t8 = tid >> 3, sl = tid & 7;
    int lane = tid & 63, w = tid >> 6;
    int r0 = lane & 15, gq = lane >> 4;
    int tblk = blockIdx.x / 313;

    f32x4 acc[4][4] = {};

    for (int k0 = 0; k0 < K; k0 += 64) {
#pragma unroll
        for (int i = 0; i < 2; ++i) {
            int r = i * 32 + t8;
            int ch = sl ^ (r & 7);
            gload16(A + (size_t)(bm + r) * K + k0 + ch * 8, &As[i * 2048 + tid * 8]);
        }
#pragma unroll
        for (int i = 0; i < 8; ++i) {
            int r = i * 32 + t8;
            int ch = sl ^ (r & 7);
            gload16(Bt + (size_t)r * K + k0 + ch * 8, &Bs[i * 2048 + tid * 8]);
        }
        __syncthreads();
#pragma unroll
        for (int kk = 0; kk < 2; ++kk) {
            bf16x8 a[4], b[4];
#pragma unroll
            for (int mi = 0; mi < 4; ++mi) {
                int R = mi * 16 + r0;
                int s = (kk * 4 + gq) ^ (R & 7);
                a[mi] = *(const bf16x8*)&As[R * 64 + s * 8];
            }
#pragma unroll
            for (int ni = 0; ni < 4; ++ni) {
                int R = w * 64 + ni * 16 + r0;
                int s = (kk * 4 + gq) ^ (R & 7);
                b[ni] = *(const bf16x8*)&Bs[R * 64 + s * 8];
            }
#pragma unroll
            for (int mi = 0; mi < 4; ++mi)
#pragma unroll
                for (int ni = 0; ni < 4; ++ni)
                    acc[mi][ni] = __builtin_amdgcn_mfma_f32_16x16x32_bf16(
                        a[mi], b[ni], acc[mi][ni], 0, 0, 0);
        }
        __syncthreads();
    }

    if (!POOL) {
#pragma unroll
        for (int ni = 0; ni < 4; ++ni) {
            int colg = w * 64 + ni * 16 + r0;
            float b = bias[colg];
#pragma unroll
            for (int mi = 0; mi < 4; ++mi) {
                int rbase = bm + mi * 16 + gq * 4;
#pragma unroll
                for (int q = 0; q < 4; ++q) {
                    int row = rbase + q;
                    int rloc = row - tblk * MPAD;
                    float sc = (rloc < NNODES) ? dscale[tblk * NNODES + rloc] : 0.f;
                    C[(size_t)row * HG + colg] = f2bf(sc * fmaxf(acc[mi][ni][q] + b, 0.f));
                }
            }
        }
    } else {
        csum[tid] = 0.f;
        __syncthreads();
#pragma unroll
        for (int ni = 0; ni < 4; ++ni) {
            int colg = w * 64 + ni * 16 + r0;
            float b = bias[colg];
            float s = 0.f;
#pragma unroll
            for (int mi = 0; mi < 4; ++mi) {
                int rbase = bm + mi * 16 + gq * 4;
#pragma unroll
                for (int q = 0; q < 4; ++q) {
                    int row = rbase + q;
                    int rloc = row - tblk * MPAD;
                    if (rloc < NNODES) s += fmaxf(acc[mi][ni][q] + b, 0.f);
                }
            }
            atomicAdd(&csum[colg], s);
        }
        __syncthreads();
        atomicAdd(&pool[tblk * HG + tid], csum[tid]);
    }
}

// ---------------- layer-0 input projection ----------------

__global__ void __launch_bounds__(128) pre0_kernel(const float* __restrict__ pooled,
        const float* __restrict__ Wih0, const float* __restrict__ bih0,
        const float* __restrict__ bhh0, float* __restrict__ pre0) {
    int j = blockIdx.x * 128 + threadIdx.x;
    const float4* w = (const float4*)(Wih0 + (size_t)j * HG);
    float acc[T_STEPS];
#pragma unroll
    for (int t = 0; t < T_STEPS; ++t) acc[t] = 0.f;
    for (int i = 0; i < 64; ++i) {
        float4 wv = w[i];
#pragma unroll
        for (int t = 0; t < T_STEPS; ++t) {
            float4 pv = *(const float4*)&pooled[t * HG + i * 4];
            acc[t] += pv.x * wv.x + pv.y * wv.y + pv.z * wv.z + pv.w * wv.w;
        }
    }
    float b = bih0[j] + bhh0[j];
#pragma unroll
    for (int t = 0; t < T_STEPS; ++t)
        pre0[t * 1024 + j] = acc[t] * (1.f / (float)NNODES) + b;
}

// ---------------- 4-block cooperative LSTM (verified R5/R6) ----------------

__device__ __forceinline__ void run_layer(const float* __restrict__ W,
        const float* preSrc, int preStride,
        int r, int tid, int b, int sbase, bool save_hseq,
        float* hl, float* garr,
        float* hbuf, float* hseq_glob, int* flags) {
    int u = tid & 63;
    u32 wreg[128];
    {
        const float4* src = (const float4*)(W + (size_t)r * HG);
#pragma unroll
        for (int i = 0; i < 64; ++i) {
            float4 v = src[i];
            wreg[2 * i]     = (u32)f2h(v.x) | ((u32)f2h(v.y) << 16);
            wreg[2 * i + 1] = (u32)f2h(v.z) | ((u32)f2h(v.w) << 16);
        }
    }
    float c = 0.f;
    hl[tid] = 0.f;
    __syncthreads();
    for (int t = 0; t < T_STEPS; ++t) {
        int s = sbase + t + 1;
        float pv = preSrc[t * preStride];
        float acc = 0.f;
#pragma unroll
        for (int k2 = 0; k2 < 128; ++k2) {
            u32 w = wreg[k2];
            float2 hv = *(const float2*)&hl[k2 * 2];
            acc += h2f((u16)w) * hv.x + h2f((u16)(w >> 16)) * hv.y;
        }
        garr[tid] = acc + pv;
        __syncthreads();
        if (tid < 64) {
            float ig = sigm(garr[u]);
            float fg = sigm(garr[64 + u]);
            float gg = tanhf(garr[128 + u]);
            float og = sigm(garr[192 + u]);
            c = fg * c + ig * gg;
            float hn = og * tanhf(c);
            astore(&hbuf[(s & 1) * 256 + b * 64 + u], hn);
            if (save_hseq) astore(&hseq_glob[t * 256 + b * 64 + u], hn);
        }
        if (tid == 0)
            __hip_atomic_store(&flags[b], s, __ATOMIC_RELEASE, __HIP_MEMORY_SCOPE_AGENT);
        if (tid < 4) {
            while (__hip_atomic_load(&flags[tid], __ATOMIC_ACQUIRE,
                                     __HIP_MEMORY_SCOPE_AGENT) < s)
                __builtin_amdgcn_s_sleep(1);
        }
        __syncthreads();
        hl[tid] = aload(&hbuf[(s & 1) * 256 + tid]);
        __syncthreads();
    }
}

__global__ void __launch_bounds__(256, 1) lstm4(
        const float* __restrict__ pre0,
        const float* __restrict__ Whh0, const float* __restrict__ Wih1,
        const float* __restrict__ Whh1,
        const float* __restrict__ bih1, const float* __restrict__ bhh1,
        const float* __restrict__ Wlin, const float* __restrict__ blin,
        float* hbuf, float* hseq_glob, int* flags,
        float* __restrict__ out) {
    __shared__ float hseqL[T_STEPS * 256];
    __shared__ float pre1L[T_STEPS * 256];
    __shared__ float hl[256];
    __shared__ float garr[256];
    int tid = threadIdx.x;
    int b = blockIdx.x;
    int g = tid >> 6, u = tid & 63;
    int r = g * 256 + b * 64 + u;

    run_layer(Whh0, pre0 + r, 1024, r, tid, b, 0, true,
              hl, garr, hbuf, hseq_glob, flags);

    for (int i = tid; i < T_STEPS * 256; i += 256)
        hseqL[i] = aload(&hseq_glob[i]);
    __syncthreads();

    {
        float pre1[T_STEPS];
#pragma unroll
        for (int t = 0; t < T_STEPS; ++t) pre1[t] = 0.f;
        const float4* src = (const float4*)(Wih1 + (size_t)r * HG);
        for (int i = 0; i < 64; ++i) {
            float4 wv = src[i];
#pragma unroll
            for (int t = 0; t < T_STEPS; ++t) {
                float4 hv = *(const float4*)&hseqL[t * 256 + i * 4];
                pre1[t] += wv.x * hv.x + wv.y * hv.y + wv.z * hv.z + wv.w * hv.w;
            }
        }
        float bias1 = bih1[r] + bhh1[r];
        __syncthreads();
#pragma unroll
        for (int t = 0; t < T_STEPS; ++t) pre1L[t * 256 + tid] = pre1[t] + bias1;
        __syncthreads();
    }

    run_layer(Whh1, pre1L + tid, 256, r, tid, b, T_STEPS, false,
              hl, garr, hbuf, hseq_glob, flags);

    if (b == 0) {
        float hv = hl[tid];
        for (int j = 0; j < 8; ++j) {
            garr[tid] = hv * Wlin[j * 256 + tid];
            __syncthreads();
            if (tid < 128) garr[tid] += garr[tid + 128];
            __syncthreads();
            if (tid < 64) {
                float v = garr[tid] + garr[tid + 64];
                for (int off = 32; off; off >>= 1) v += __shfl_down(v, off);
                if (tid == 0) out[j] = v + blin[j];
            }
            __syncthreads();
        }
    }
}

// ---------------- orchestration ----------------

extern "C" void kernel_launch(void* const* d_in, const int* in_sizes, int n_in,
                              void* d_out, int out_size, void* d_ws, size_t ws_size,
                              hipStream_t stream) {
    const float* x    = (const float*)d_in[0];
    const int*   edges= (const int*)d_in[1];
    const float* W1   = (const float*)d_in[3];
    const float* b1   = (const float*)d_in[4];
    const float* W2   = (const float*)d_in[5];
    const float* b2   = (const float*)d_in[6];
    const float* Wih0 = (const float*)d_in[7];
    const float* Whh0 = (const float*)d_in[8];
    const float* bih0 = (const float*)d_in[9];
    const float* bhh0 = (const float*)d_in[10];
    const float* Wih1 = (const float*)d_in[11];
    const float* Whh1 = (const float*)d_in[12];
    const float* bih1 = (const float*)d_in[13];
    const float* bhh1 = (const float*)d_in[14];
    const float* Wlin = (const float*)d_in[15];
    const float* blin = (const float*)d_in[16];
    (void)in_sizes; (void)n_in; (void)out_size;

    char* p = (char*)d_ws;
    auto alloc = [&](size_t bytes) -> char* {
        char* q = p; p += (bytes + 255) & ~(size_t)255; return q;
    };
    int*   hist     = (int*)  alloc(sizeof(int)   * T_STEPS * NNODES);
    int*   rowstart = (int*)  alloc(sizeof(int)   * T_STEPS * RS_STRIDE);
    float* dinv     = (float*)alloc(sizeof(float) * T_STEPS * NNODES);
    int*   col      = (int*)  alloc(sizeof(int)   * T_STEPS * NEDGES);
    float* pooled   = (float*)alloc(sizeof(float) * T_STEPS * HG);
    u16*   W1t      = (u16*)  alloc(sizeof(u16)   * HG * FIN);
    u16*   W2t      = (u16*)  alloc(sizeof(u16)   * HG * HG);
    float* pre0     = (float*)alloc(sizeof(float) * T_STEPS * 1024);
    float* hbuf     = (float*)alloc(sizeof(float) * 2 * 256);
    float* hseq_g   = (float*)alloc(sizeof(float) * T_STEPS * 256);
    int*   flags    = (int*)  alloc(sizeof(int)   * 4);
    size_t fixed_used = (size_t)(p - (char*)d_ws);

    const size_t xb_bytes  = sizeof(u16) * (size_t)T_STEPS * NNODES * FIN;
    const size_t per_g     = (size_t)MPAD * HG * 2 * 2;
    const size_t slack     = 4096 * 16;
    static const int gopts[6] = {12, 6, 4, 3, 2, 1};
    int G = 1;
    for (int i = 0; i < 6; ++i)
        if (fixed_used + xb_bytes + per_g * gopts[i] + slack <= ws_size) { G = gopts[i]; break; }
    u16* xb   = (u16*)alloc(xb_bytes);
    u16* h1b  = (u16*)alloc(sizeof(u16) * (size_t)G * MPAD * HG);
    u16* aggu = (u16*)alloc(sizeof(u16) * (size_t)G * MPAD * HG);

    hipMemsetAsync(hist, 0, sizeof(int) * T_STEPS * NNODES, stream);
    hipMemsetAsync(pooled, 0, sizeof(float) * T_STEPS * HG, stream);
    hipMemsetAsync(flags, 0, sizeof(int) * 4, stream);

    int tot = T_STEPS * NEDGES;
    hist_kernel<<<(tot + 255) / 256, 256, 0, stream>>>(edges, hist);
    scan_kernel<<<T_STEPS, 1024, 0, stream>>>(hist, rowstart, dinv);
    fill_kernel<<<(tot + 255) / 256, 256, 0, stream>>>(edges, rowstart, hist, col);
    convw_kernel<<<HG * FIN / 256, 256, 0, stream>>>(W1, W1t, FIN);
    convw_kernel<<<HG * HG  / 256, 256, 0, stream>>>(W2, W2t, HG);
    x2bf_kernel<<<T_STEPS * NNODES * 32 / 256, 256, 0, stream>>>(x, dinv, xb);

    constexpr int NQ = MPAD / 4;
    for (int g = 0; g < T_STEPS / G; ++g) {
        int t0 = g * G;
        const u16*   xbg = xb + (size_t)t0 * NNODES * FIN;
        const int*   rsg = rowstart + (size_t)t0 * RS_STRIDE;
        const int*   clg = col + (size_t)t0 * NEDGES;
        const float* dvg = dinv + (size_t)t0 * NNODES;
        agg_slice<FIN, 2, false><<<G * 2 * NQ, 64, 0, stream>>>(
                xbg, rsg, clg, dvg, aggu);
        gemm_bf16<FIN, false><<<G * 313, 256, 0, stream>>>(aggu, W1t, b1, dvg,
                h1b, nullptr);
        agg_slice<HG, 4, true><<<G * 4 * NQ, 64, 0, stream>>>(
                h1b, rsg, clg, dvg, aggu);
        gemm_bf16<HG, true><<<G * 313, 256, 0, stream>>>(aggu, W2t, b2, nullptr,
                nullptr, pooled + (size_t)t0 * HG);
    }
    pre0_kernel<<<8, 128, 0, stream>>>(pooled, Wih0, bih0, bhh0, pre0);
    lstm4<<<4, 256, 0, stream>>>(pre0, Whh0, Wih1, Whh1, bih1, bhh1, Wlin, blin,
                                 hbuf, hseq_g, flags, (float*)d_out);
}